// Round 4
// baseline (45531.790 us; speedup 1.0000x reference)
//
#include <hip/hip_runtime.h>
#include <stdint.h>

// ---------------------------------------------------------------------------
// Bidirectional 2-layer LSTM.
//  Phase A (parallel): xg = x . W_ih^T + b (bf16 MFMA GEMM), stored in the
//    scan-consumption layout: per (t, mh, half, w) a 2KB chunk; per lane 32B
//    = [g(4)][r(4)] bf16, loaded by the scan as 2x dwordx4.
//    Weights/bias pre-scaled by log2e (i,f,o) / 2*log2e (g) -> bare v_exp_f32.
//  Phase B (scan): 8 WGs = (2 directions) x (2 batch-halves) x (2 UNIT-halves).
//    Each wave owns 16 units x ALL 4 gates resident in 128 VGPRs -> zero
//    weight traffic. LDS = only the 2x4KB h double-buffer (XOR-swizzled,
//    conflict-free). Partner unit-half WGs exchange 4KB of h per step through
//    L2: relaxed agent atomic stores -> per-wave vmcnt(0) -> s_barrier ->
//    single release flag; consumer polls flag then L1-bypassing atomic loads.
//    Own-half ki slices (from LDS) compute first to hide partner L2 latency.
// MFMA 16x16x32 bf16:  A: (m=lane&15, k=quad*8+j)  B: (k=quad*8+j, n=lane&15)
//                      C/D: (row=quad*4+reg, col=lane&15)
// ---------------------------------------------------------------------------

#define Bn 32
#define Tn 2048
#define Hn 256

#define L2E 1.4426950408889634f   // log2(e)
#define L2E2 2.8853900817779268f  // 2*log2(e)

typedef short short8 __attribute__((ext_vector_type(8)));
typedef float f32x4 __attribute__((ext_vector_type(4)));
typedef unsigned int u32x4 __attribute__((ext_vector_type(4)));

extern "C" __device__ float __ocml_native_exp2_f32(float);

__device__ inline unsigned short f2b(float f) {  // fp32 -> bf16 RNE
  union { float f; unsigned u; } v; v.f = f;
  unsigned r = v.u + 0x7fffu + ((v.u >> 16) & 1u);
  return (unsigned short)(r >> 16);
}
__device__ inline float asf(unsigned u) {
  union { unsigned u; float f; } v; v.u = u; return v.f;
}

// ---------------- Phase A: xg = A . W^T + b  ------------------------------
template <int K, bool AF32>
__global__ __launch_bounds__(256, 2) void xg_gemm(
    const void* __restrict__ Ain,
    const float* __restrict__ Wf, const float* __restrict__ bf_,
    const float* __restrict__ Wr, const float* __restrict__ br_,
    unsigned short* __restrict__ xg) {
  constexpr int KI = K / 32;
  const int bid = blockIdx.x;
  const int scan = bid & 1;
  const int sgrp = (bid >> 1) & 7;
  const int mchunk = bid >> 4;           // 0..255
  const int wave = threadIdx.x >> 6;
  const int lane = threadIdx.x & 63;
  const int l15 = lane & 15, quad = lane >> 4;
  const int stripe = sgrp * 4 + wave;    // 0..31 -> 32 gate-cols each
  const int gi0 = stripe * 32;
  const int gg = stripe >> 3;            // gate index (uniform per stripe)

  const float* W = scan ? Wr : Wf;
  const float* bias = scan ? br_ : bf_;
  const float gscale = (gg == 2) ? L2E2 : L2E;  // exp2-folding pre-scale

  short8 bfr[KI][2];
  float bias2[2];
#pragma unroll
  for (int sub = 0; sub < 2; ++sub) {
    const int gi = gi0 + sub * 16 + l15;
    bias2[sub] = bias[gi] * gscale;
#pragma unroll
    for (int ki = 0; ki < KI; ++ki) {
      const float* src = W + (size_t)gi * K + ki * 32 + quad * 8;
      short8 v;
#pragma unroll
      for (int j = 0; j < 8; ++j) v[j] = (short)f2b(src[j] * gscale);
      bfr[ki][sub] = v;
    }
  }

  const size_t scanoff = (size_t)scan << 26;  // elements (128MB per scan)
#pragma unroll 1
  for (int mt0 = 0; mt0 < 16; ++mt0) {
    const int mt = mchunk * 16 + mt0;
    const size_t row = (size_t)mt * 16 + l15;
    f32x4 acc[2];
#pragma unroll
    for (int sub = 0; sub < 2; ++sub) {
      f32x4 bi = {bias2[sub], bias2[sub], bias2[sub], bias2[sub]};
      acc[sub] = bi;
    }
#pragma unroll
    for (int ki = 0; ki < KI; ++ki) {
      short8 af;
      if constexpr (AF32) {
        const float* ap = (const float*)Ain + row * K + ki * 32 + quad * 8;
        f32x4 a0 = *(const f32x4*)ap;
        f32x4 a1 = *(const f32x4*)(ap + 4);
#pragma unroll
        for (int j = 0; j < 4; ++j) { af[j] = (short)f2b(a0[j]); af[4 + j] = (short)f2b(a1[j]); }
      } else {
        const unsigned short* ap = (const unsigned short*)Ain + row * K + ki * 32 + quad * 8;
        af = *(const short8*)ap;
      }
#pragma unroll
      for (int sub = 0; sub < 2; ++sub)
        acc[sub] = __builtin_amdgcn_mfma_f32_16x16x32_bf16(af, bfr[ki][sub], acc[sub], 0, 0, 0);
    }
    // scan layout: G = stripe*2+sub -> g=G>>4, half=(G>>3)&1, w=G&7
    // idx = scanoff + (t*2+mh)*16384 + half*8192 + w*1024
    //       + ((b&15)>>2)*256 + l15*16 + g*4 + (b&3)
#pragma unroll
    for (int sub = 0; sub < 2; ++sub) {
      const int G = stripe * 2 + sub;
      const int g_s = G >> 4, half_s = (G >> 3) & 1, w_s = G & 7;
#pragma unroll
      for (int r = 0; r < 4; ++r) {
        const int orow = mt * 16 + quad * 4 + r;
        const int m = orow >> 11, t = orow & 2047;
        size_t idx = scanoff
          + (((size_t)t * 2 + (m >> 4)) << 14)
          + (half_s << 13) + (w_s << 10)
          + (((m >> 2) & 3) << 8) + (l15 << 4) + (g_s << 2) + (m & 3);
        xg[idx] = f2b(acc[sub][r]);
      }
    }
  }
}

// ---------------- Phase B: recurrent scan (8 WGs, pairwise h-exchange) -----
// bid: scan = bid&1, mh = (bid>>1)&1, half = bid>>2.  512 threads = 8 waves.
template <bool LAYER1>
__global__ __launch_bounds__(512, 2) void lstm_scan(
    const unsigned short* __restrict__ xg,   // scan layout, bf16
    const float* __restrict__ Whh_f, const float* __restrict__ Whh_r,
    unsigned short* __restrict__ hx,         // [8 slot][2 parity][16][128] bf16
    int* __restrict__ flags,                 // [8] per layer
    unsigned short* __restrict__ h0out,      // [B][T][512] bf16 (layer0)
    float* __restrict__ dout) {              // [B][T][512] f32  (layer1)
  __shared__ __align__(16) char smem[2 * 4096];  // h double buffer (swizzled)

  const int bid = blockIdx.x;
  const int scan = bid & 1;
  const int mh = (bid >> 1) & 1;           // batch half (16 rows)
  const int half = bid >> 2;               // unit half (128 units)
  const int wave = threadIdx.x >> 6;
  const int lane = threadIdx.x & 63;
  const int l15 = lane & 15, quad = lane >> 4;

  const float* Whh = scan ? Whh_r : Whh_f;

  // ---- resident W_hh: 16 owned units x 4 gates x K=256 -> 128 VGPR ----
  short8 wres[4][8];
#pragma unroll
  for (int g = 0; g < 4; ++g) {
    const float ws = (g == 2) ? L2E2 : L2E;
#pragma unroll
    for (int ki = 0; ki < 8; ++ki) {
      const int col = g * Hn + half * 128 + wave * 16 + l15;
      const float* src = Whh + ((size_t)col << 8) + ki * 32 + quad * 8;
      f32x4 v0 = *(const f32x4*)src;
      f32x4 v1 = *(const f32x4*)(src + 4);
      short8 v;
#pragma unroll
      for (int j = 0; j < 4; ++j) { v[j] = (short)f2b(v0[j] * ws); v[4 + j] = (short)f2b(v1[j] * ws); }
      wres[g][ki] = v;
    }
  }

  const int slot = (scan * 2 + mh) * 2 + half;
  const int pslot = slot ^ 1;
  unsigned short* hxw = hx + (size_t)slot * 4096;        // + parity*2048 elems
  const unsigned short* hxp = hx + (size_t)pslot * 4096;
  int* myflag = flags + slot;
  int* pflag = flags + pslot;

  // ---- xg addressing + t0 prefetch ----
  const size_t scanoff = (size_t)scan << 26;
  const int tstep = scan ? -1 : 1;
  const int t0 = scan ? (Tn - 1) : 0;
  const size_t xbase0 = scanoff + ((size_t)half << 13) + ((size_t)wave << 10) + (size_t)lane * 16;
  u32x4 xr[2];
  {
    const unsigned short* xb = xg + xbase0 + (((size_t)t0 * 2 + mh) << 14);
    xr[0] = *(const u32x4*)(xb + 0);
    xr[1] = *(const u32x4*)(xb + 8);
  }

  float c_st[4] = {0.f, 0.f, 0.f, 0.f};
  const int ob = half ? 4 : 0;   // own global-ki base (k ordered by unit)
  const int pb = half ? 0 : 4;   // partner global-ki base

  __syncthreads();

#pragma unroll 1
  for (int s = 0; s < Tn; ++s) {
    const int t = scan ? (Tn - 1 - s) : s;
    const int tn = (s < Tn - 1) ? (t + tstep) : t;
    const int p_r = (s - 1) & 1, p_w = s & 1;

    // [A] acc init from xg; then refill prefetch for next t
    f32x4 acc[4];
#pragma unroll
    for (int g = 0; g < 4; ++g) {
#pragma unroll
      for (int r = 0; r < 4; ++r) {
        const int e = g * 4 + r;
        const unsigned w32 = xr[e >> 3][(e >> 1) & 3];
        acc[g][r] = (r & 1) ? asf(w32 & 0xffff0000u) : asf(w32 << 16);
      }
    }
    {
      const unsigned short* xbn = xg + xbase0 + (((size_t)tn * 2 + mh) << 14);
      xr[0] = *(const u32x4*)(xbn + 0);
      xr[1] = *(const u32x4*)(xbn + 8);
    }

    // [B] h_{s-1} @ W_hh^T
    if (s > 0) {
      // own-half fragments from LDS -- issued before the poll
      const char* hr = smem + p_r * 4096;
      short8 a_own[4];
#pragma unroll
      for (int kil = 0; kil < 4; ++kil) {
        int byt = l15 * 256 + kil * 64 + quad * 16;
        byt ^= (l15 & 7) << 4;               // XOR-swizzle (write side matches)
        a_own[kil] = *(const short8*)(hr + byt);
      }
      // partner release flag
      for (;;) {
        int v = __hip_atomic_load(pflag, __ATOMIC_RELAXED, __HIP_MEMORY_SCOPE_AGENT);
        if (v >= s) break;
        __builtin_amdgcn_s_sleep(1);
      }
      // partner-half fragments via L1-bypassing agent atomics
      const unsigned long long* pq = (const unsigned long long*)(hxp + p_r * 2048);
      unsigned long long q[4][2];
#pragma unroll
      for (int kil = 0; kil < 4; ++kil) {
        const int ei = (l15 * 128 + kil * 32 + quad * 8) >> 2;
        q[kil][0] = __hip_atomic_load(pq + ei, __ATOMIC_RELAXED, __HIP_MEMORY_SCOPE_AGENT);
        q[kil][1] = __hip_atomic_load(pq + ei + 1, __ATOMIC_RELAXED, __HIP_MEMORY_SCOPE_AGENT);
      }
      // own-half MFMAs first (hide partner L2 latency)
#pragma unroll
      for (int kil = 0; kil < 4; ++kil) {
        const short8 a = a_own[kil];
        acc[0] = __builtin_amdgcn_mfma_f32_16x16x32_bf16(a, wres[0][ob + kil], acc[0], 0, 0, 0);
        acc[1] = __builtin_amdgcn_mfma_f32_16x16x32_bf16(a, wres[1][ob + kil], acc[1], 0, 0, 0);
        acc[2] = __builtin_amdgcn_mfma_f32_16x16x32_bf16(a, wres[2][ob + kil], acc[2], 0, 0, 0);
        acc[3] = __builtin_amdgcn_mfma_f32_16x16x32_bf16(a, wres[3][ob + kil], acc[3], 0, 0, 0);
      }
#pragma unroll
      for (int kil = 0; kil < 4; ++kil) {
        union { unsigned long long qq[2]; short8 s8; } u;
        u.qq[0] = q[kil][0]; u.qq[1] = q[kil][1];
        const short8 a = u.s8;
        acc[0] = __builtin_amdgcn_mfma_f32_16x16x32_bf16(a, wres[0][pb + kil], acc[0], 0, 0, 0);
        acc[1] = __builtin_amdgcn_mfma_f32_16x16x32_bf16(a, wres[1][pb + kil], acc[1], 0, 0, 0);
        acc[2] = __builtin_amdgcn_mfma_f32_16x16x32_bf16(a, wres[2][pb + kil], acc[2], 0, 0, 0);
        acc[3] = __builtin_amdgcn_mfma_f32_16x16x32_bf16(a, wres[3][pb + kil], acc[3], 0, 0, 0);
      }
    }

    // [D] gates + state ; h -> LDS + partner hx + output
#pragma unroll
    for (int r = 0; r < 4; ++r) {
      float e0 = __ocml_native_exp2_f32(-acc[0][r]);   // i
      float e1 = __ocml_native_exp2_f32(-acc[1][r]);   // f
      float e2 = __ocml_native_exp2_f32(-acc[2][r]);   // g (2log2e scale)
      float e3 = __ocml_native_exp2_f32(-acc[3][r]);   // o
      float a0 = 1.f + e0, a1 = 1.f + e1, a2 = 1.f + e2, a3 = 1.f + e3;
      float r02 = __builtin_amdgcn_rcpf(a0 * a2);
      float tig = __builtin_fmaf(e2, -L2E2, L2E2) * r02;   // 2log2e*sig(i)tanh(g)
      float rf = __builtin_amdgcn_rcpf(a1);                // sig(f)
      float cs = __builtin_fmaf(rf, c_st[r], tig);         // 2log2e * c
      c_st[r] = cs;
      float e4 = __ocml_native_exp2_f32(-cs);
      float r34 = __builtin_amdgcn_rcpf(a3 * (1.f + e4));
      float hv = (1.f - e4) * r34;                         // sig(o)*tanh(c)
      unsigned short h16 = f2b(hv);
      int pk = __shfl_xor((int)h16, 1);
      const int row = quad * 4 + r;
      const int ul = (wave << 4) + l15;                    // owned unit (local)
      const unsigned pv = (unsigned)h16 | ((unsigned)pk << 16);
      if (!(lane & 1)) {
        int lb = p_w * 4096 + row * 256 + ul * 2;
        lb ^= (row & 7) << 4;                              // XOR-swizzle
        *(unsigned*)(smem + lb) = pv;
        __hip_atomic_store((unsigned*)(hxw + p_w * 2048 + row * 128 + ul),
                           pv, __ATOMIC_RELAXED, __HIP_MEMORY_SCOPE_AGENT);
      }
      const int b = mh * 16 + row;
      const size_t oidx = (((size_t)b * Tn + t) << 9) + scan * Hn + half * 128 + ul;
      if constexpr (!LAYER1) {
        if (!(lane & 1)) *(unsigned*)(h0out + oidx) = pv;
      } else {
        float pkf = __shfl_xor(hv, 1);
        if (!(lane & 1)) { float2 st = {hv, pkf}; *(float2*)(dout + oidx) = st; }
      }
    }

    // release: all waves drain LDS+global stores, then one flag store
    asm volatile("s_waitcnt vmcnt(0) lgkmcnt(0)" ::: "memory");
    __builtin_amdgcn_s_barrier();
    __builtin_amdgcn_sched_barrier(0);
    if (threadIdx.x == 0)
      __hip_atomic_store(myflag, s + 1, __ATOMIC_RELAXED, __HIP_MEMORY_SCOPE_AGENT);
  }
}

extern "C" void kernel_launch(void* const* d_in, const int* in_sizes, int n_in,
                              void* d_out, int out_size, void* d_ws, size_t ws_size,
                              hipStream_t stream) {
  (void)in_sizes; (void)n_in; (void)out_size; (void)ws_size;
  const float* x      = (const float*)d_in[0];
  const float* Wih_f0 = (const float*)d_in[1];
  const float* Whh_f0 = (const float*)d_in[2];
  const float* b_f0   = (const float*)d_in[3];
  const float* Wih_r0 = (const float*)d_in[4];
  const float* Whh_r0 = (const float*)d_in[5];
  const float* b_r0   = (const float*)d_in[6];
  const float* Wih_f1 = (const float*)d_in[7];
  const float* Whh_f1 = (const float*)d_in[8];
  const float* b_f1   = (const float*)d_in[9];
  const float* Wih_r1 = (const float*)d_in[10];
  const float* Whh_r1 = (const float*)d_in[11];
  const float* b_r1   = (const float*)d_in[12];

  char* ws = (char*)d_ws;
  unsigned short* xgbuf = (unsigned short*)ws;                 // 268,435,456 B
  size_t off = (size_t)2 * Tn * Bn * 1024 * sizeof(unsigned short);
  unsigned short* h0out = (unsigned short*)(ws + off);         // 67,108,864 B
  off += (size_t)Bn * Tn * 512 * sizeof(unsigned short);
  unsigned short* hxbuf = (unsigned short*)(ws + off);         // 65,536 B
  off += 65536;
  int* flagsA = (int*)(ws + off);                              // 8 + 8 ints
  int* flagsB = flagsA + 8;

  hipMemsetAsync(flagsA, 0, 64, stream);

  dim3 blkA(256), blkB(512);
  // layer 0
  xg_gemm<256, true><<<dim3(4096), blkA, 0, stream>>>(
      (const void*)x, Wih_f0, b_f0, Wih_r0, b_r0, xgbuf);
  lstm_scan<false><<<dim3(8), blkB, 0, stream>>>(
      xgbuf, Whh_f0, Whh_r0, hxbuf, flagsA, h0out, (float*)nullptr);
  // layer 1
  xg_gemm<512, false><<<dim3(4096), blkA, 0, stream>>>(
      (const void*)h0out, Wih_f1, b_f1, Wih_r1, b_r1, xgbuf);
  lstm_scan<true><<<dim3(8), blkB, 0, stream>>>(
      xgbuf, Whh_f1, Whh_r1, hxbuf, flagsB, (unsigned short*)nullptr, (float*)d_out);
}

// Round 5
// 23757.431 us; speedup vs baseline: 1.9165x; 1.9165x over previous
//
#include <hip/hip_runtime.h>
#include <stdint.h>

// ---------------------------------------------------------------------------
// Bidirectional 2-layer LSTM.
//  Phase A (parallel): xg = x . W_ih^T + b (bf16 MFMA GEMM), scan layout:
//    per (t, mh, cg) a 2KB chunk; per lane 32B = [g(4)][r(4)] bf16 -> the scan
//    loads its step preacts with 2x dwordx4. Weights/bias pre-scaled by log2e
//    (i,f,o) / 2*log2e (g) -> gate transcendentals are bare v_exp_f32.
//  Phase B (scan): hidden-split, 8 WGs x 512 threads. Wave = one SLOT
//    (scan = wave>>2, cg = bid*2 + ((wave&3)>>1), mh = wave&1): owns 16 units
//    x 4 gates x 16 batch rows, ALL weights resident (128 VGPR/wave), no LDS.
//    fwd+rev slots co-resident in the same WG: while one scan's waves wait in
//    poll / h-load (cross-CU LLC latency), the other scan's waves compute --
//    r4 showed the exchange stall is the whole cost when nothing hides it.
//    Per-step publish (r0-proven protocol, publish-fast ordering):
//      gates -> 4 paired-u32 agent atomic h-stores -> s_waitcnt vmcnt(0)
//      (ONLY those stores outstanding) -> slot flag store. Output stores and
//      xg prefetch issue AFTER the flag, off the critical path. Consumers:
//      poll 16 slot flags -> 16 u64 agent atomic loads -> MFMA. No barriers.
//    WAR on the h double buffer is safe: a producer writes parity p at step s
//    only after its step-s poll passed, which requires every peer to have
//    finished reading parity p at step s-1.
// MFMA 16x16x32 bf16:  A: (m=lane&15, k=quad*8+j)  B: (k=quad*8+j, n=lane&15)
//                      C/D: (row=quad*4+reg, col=lane&15)
// ---------------------------------------------------------------------------

#define Bn 32
#define Tn 2048
#define Hn 256

#define L2E 1.4426950408889634f   // log2(e)
#define L2E2 2.8853900817779268f  // 2*log2(e)

typedef short short8 __attribute__((ext_vector_type(8)));
typedef float f32x4 __attribute__((ext_vector_type(4)));
typedef unsigned int u32x4 __attribute__((ext_vector_type(4)));

extern "C" __device__ float __ocml_native_exp2_f32(float);

__device__ inline unsigned short f2b(float f) {  // fp32 -> bf16 RNE
  union { float f; unsigned u; } v; v.f = f;
  unsigned r = v.u + 0x7fffu + ((v.u >> 16) & 1u);
  return (unsigned short)(r >> 16);
}
__device__ inline float asf(unsigned u) {
  union { unsigned u; float f; } v; v.u = u; return v.f;
}

// ---------------- Phase A: xg = A . W^T + b  ------------------------------
template <int K, bool AF32>
__global__ __launch_bounds__(256, 2) void xg_gemm(
    const void* __restrict__ Ain,
    const float* __restrict__ Wf, const float* __restrict__ bf_,
    const float* __restrict__ Wr, const float* __restrict__ br_,
    unsigned short* __restrict__ xg) {
  constexpr int KI = K / 32;
  const int bid = blockIdx.x;
  const int scan = bid & 1;
  const int sgrp = (bid >> 1) & 7;
  const int mchunk = bid >> 4;           // 0..255
  const int wave = threadIdx.x >> 6;
  const int lane = threadIdx.x & 63;
  const int l15 = lane & 15, quad = lane >> 4;
  const int stripe = sgrp * 4 + wave;    // 0..31 -> 32 gate-cols each
  const int gi0 = stripe * 32;
  const int gg = stripe >> 3;            // gate index (uniform per stripe)

  const float* W = scan ? Wr : Wf;
  const float* bias = scan ? br_ : bf_;
  const float gscale = (gg == 2) ? L2E2 : L2E;  // exp2-folding pre-scale

  short8 bfr[KI][2];
  float bias2[2];
#pragma unroll
  for (int sub = 0; sub < 2; ++sub) {
    const int gi = gi0 + sub * 16 + l15;
    bias2[sub] = bias[gi] * gscale;
#pragma unroll
    for (int ki = 0; ki < KI; ++ki) {
      const float* src = W + (size_t)gi * K + ki * 32 + quad * 8;
      short8 v;
#pragma unroll
      for (int j = 0; j < 8; ++j) v[j] = (short)f2b(src[j] * gscale);
      bfr[ki][sub] = v;
    }
  }

  const size_t scanoff = (size_t)scan << 26;  // elements (128MB per scan)
#pragma unroll 1
  for (int mt0 = 0; mt0 < 16; ++mt0) {
    const int mt = mchunk * 16 + mt0;
    const size_t row = (size_t)mt * 16 + l15;
    f32x4 acc[2];
#pragma unroll
    for (int sub = 0; sub < 2; ++sub) {
      f32x4 bi = {bias2[sub], bias2[sub], bias2[sub], bias2[sub]};
      acc[sub] = bi;
    }
#pragma unroll
    for (int ki = 0; ki < KI; ++ki) {
      short8 af;
      if constexpr (AF32) {
        const float* ap = (const float*)Ain + row * K + ki * 32 + quad * 8;
        f32x4 a0 = *(const f32x4*)ap;
        f32x4 a1 = *(const f32x4*)(ap + 4);
#pragma unroll
        for (int j = 0; j < 4; ++j) { af[j] = (short)f2b(a0[j]); af[4 + j] = (short)f2b(a1[j]); }
      } else {
        const unsigned short* ap = (const unsigned short*)Ain + row * K + ki * 32 + quad * 8;
        af = *(const short8*)ap;
      }
#pragma unroll
      for (int sub = 0; sub < 2; ++sub)
        acc[sub] = __builtin_amdgcn_mfma_f32_16x16x32_bf16(af, bfr[ki][sub], acc[sub], 0, 0, 0);
    }
    // scan layout: G = stripe*2+sub; col = G*16+l15 -> gate = G>>4, cg = G&15
    // idx = scanoff + (t*2+mh)*16384 + cg*1024 + quad'*256 + l15*16 + g*4 + r'
#pragma unroll
    for (int sub = 0; sub < 2; ++sub) {
      const int G = stripe * 2 + sub;
#pragma unroll
      for (int r = 0; r < 4; ++r) {
        const int orow = mt * 16 + quad * 4 + r;
        const int m = orow >> 11, t = orow & 2047;
        size_t idx = scanoff
          + (((size_t)t * 2 + (m >> 4)) << 14)
          + ((size_t)(G & 15) << 10)
          + (((m >> 2) & 3) << 8) + (l15 << 4) + ((G >> 4) << 2) + (m & 3);
        xg[idx] = f2b(acc[sub][r]);
      }
    }
  }
}

// ---------------- Phase B: recurrent scan (hidden-split, fused fwd+rev) ----
// grid = 8 x 512.  wave -> slot: scan = wave>>2, cg = bid*2+((wave&3)>>1),
// mh = wave&1.  No LDS; weights fully resident; flags+hx in L2/LLC.
template <bool LAYER1>
__global__ __launch_bounds__(512, 2) void lstm_scan(
    const unsigned short* __restrict__ xg,   // scan layout, bf16
    const float* __restrict__ Whh_f, const float* __restrict__ Whh_r,
    unsigned short* __restrict__ hx,         // [2scan][2par][2mh][16][256] bf16
    int* __restrict__ flags,                 // [2scan][32] per layer
    unsigned short* __restrict__ h0out,      // [B][T][512] bf16 (layer0)
    float* __restrict__ dout) {              // [B][T][512] f32  (layer1)
  const int bid = blockIdx.x;
  const int wave = threadIdx.x >> 6;
  const int lane = threadIdx.x & 63;
  const int l15 = lane & 15, quad = lane >> 4;
  const int scan = wave >> 2;
  const int w2 = wave & 3;
  const int cg = bid * 2 + (w2 >> 1);      // 0..15 unit group
  const int mh = w2 & 1;                   // batch half
  const int U = cg * 16 + l15;             // owned unit

  const float* Whh = scan ? Whh_r : Whh_f;

  // ---- resident W_hh: 16 units x 4 gates x K=256 -> 128 VGPR/wave ----
  short8 wres[4][8];
#pragma unroll
  for (int g = 0; g < 4; ++g) {
    const float ws = (g == 2) ? L2E2 : L2E;
#pragma unroll
    for (int ki = 0; ki < 8; ++ki) {
      const float* src = Whh + ((size_t)(g * Hn + U) << 8) + ki * 32 + quad * 8;
      f32x4 v0 = *(const f32x4*)src;
      f32x4 v1 = *(const f32x4*)(src + 4);
      short8 v;
#pragma unroll
      for (int j = 0; j < 4; ++j) { v[j] = (short)f2b(v0[j] * ws); v[4 + j] = (short)f2b(v1[j] * ws); }
      wres[g][ki] = v;
    }
  }

  // ---- xg addressing + t0 prefetch ----
  const size_t scanoff = (size_t)scan << 26;
  const int tstep = scan ? -1 : 1;
  const int t0 = scan ? (Tn - 1) : 0;
  const size_t xlane = ((size_t)cg << 10) + (size_t)lane * 16;
  u32x4 xr[2];
  {
    const unsigned short* xb = xg + scanoff + (((size_t)t0 * 2 + mh) << 14) + xlane;
    xr[0] = *(const u32x4*)(xb + 0);
    xr[1] = *(const u32x4*)(xb + 8);
  }

  int* const fmine = flags + scan * 32 + cg * 2 + mh;
  int* const fpoll = flags + scan * 32 + mh;          // + lane*2, lane<16
  float c_st[4] = {0.f, 0.f, 0.f, 0.f};

#pragma unroll 1
  for (int s = 0; s < Tn; ++s) {
    const int t = scan ? (Tn - 1 - s) : s;
    const int tn = (s < Tn - 1) ? (t + tstep) : t;
    const int p_r = (s - 1) & 1, p_w = s & 1;

    // [A] acc init from xg regs (prefetched last step)
    f32x4 acc[4];
#pragma unroll
    for (int g = 0; g < 4; ++g) {
#pragma unroll
      for (int r = 0; r < 4; ++r) {
        const int e = g * 4 + r;
        const unsigned w32 = xr[e >> 3][(e >> 1) & 3];
        acc[g][r] = (r & 1) ? asf(w32 & 0xffff0000u) : asf(w32 << 16);
      }
    }

    // [B] wait peers, load h_{s-1}, MFMA
    if (s > 0) {
      for (;;) {
        int v = (lane < 16)
            ? __hip_atomic_load(fpoll + lane * 2, __ATOMIC_RELAXED, __HIP_MEMORY_SCOPE_AGENT)
            : s;
        if (__all(v >= s)) break;
        __builtin_amdgcn_s_sleep(1);
      }
      asm volatile("" ::: "memory");
      const unsigned long long* hq =
          (const unsigned long long*)hx + (size_t)(((scan * 2 + p_r) * 2) + mh) * 1024;
      unsigned long long q[8][2];
#pragma unroll
      for (int ki = 0; ki < 8; ++ki) {
        const int ei = l15 * 64 + ki * 8 + quad * 2;
        q[ki][0] = __hip_atomic_load(hq + ei, __ATOMIC_RELAXED, __HIP_MEMORY_SCOPE_AGENT);
        q[ki][1] = __hip_atomic_load(hq + ei + 1, __ATOMIC_RELAXED, __HIP_MEMORY_SCOPE_AGENT);
      }
#pragma unroll
      for (int ki = 0; ki < 8; ++ki) {
        union { unsigned long long qq[2]; short8 s8; } u;
        u.qq[0] = q[ki][0]; u.qq[1] = q[ki][1];
        const short8 a = u.s8;
        acc[0] = __builtin_amdgcn_mfma_f32_16x16x32_bf16(a, wres[0][ki], acc[0], 0, 0, 0);
        acc[1] = __builtin_amdgcn_mfma_f32_16x16x32_bf16(a, wres[1][ki], acc[1], 0, 0, 0);
        acc[2] = __builtin_amdgcn_mfma_f32_16x16x32_bf16(a, wres[2][ki], acc[2], 0, 0, 0);
        acc[3] = __builtin_amdgcn_mfma_f32_16x16x32_bf16(a, wres[3][ki], acc[3], 0, 0, 0);
      }
    }

    // [D] gates + state; h broadcast stores (publish path kept minimal)
    unsigned* hw32 = (unsigned*)hx + (size_t)(((scan * 2 + p_w) * 2) + mh) * 2048;
    unsigned pvs[4];
    float hvs[4];
#pragma unroll
    for (int r = 0; r < 4; ++r) {
      float e0 = __ocml_native_exp2_f32(-acc[0][r]);   // i
      float e1 = __ocml_native_exp2_f32(-acc[1][r]);   // f
      float e2 = __ocml_native_exp2_f32(-acc[2][r]);   // g (2log2e scale)
      float e3 = __ocml_native_exp2_f32(-acc[3][r]);   // o
      float a0 = 1.f + e0, a1 = 1.f + e1, a2 = 1.f + e2, a3 = 1.f + e3;
      float r02 = __builtin_amdgcn_rcpf(a0 * a2);
      float tig = __builtin_fmaf(e2, -L2E2, L2E2) * r02;   // 2log2e*sig(i)tanh(g)
      float rf = __builtin_amdgcn_rcpf(a1);                // sig(f)
      float cs = __builtin_fmaf(rf, c_st[r], tig);         // 2log2e * c
      c_st[r] = cs;
      float e4 = __ocml_native_exp2_f32(-cs);
      float r34 = __builtin_amdgcn_rcpf(a3 * (1.f + e4));
      float hv = (1.f - e4) * r34;                         // sig(o)*tanh(c)
      hvs[r] = hv;
      unsigned short h16 = f2b(hv);
      int pk = __shfl_xor((int)h16, 1);
      pvs[r] = (unsigned)h16 | ((unsigned)pk << 16);
      const int row = quad * 4 + r;
      if (!(lane & 1))
        __hip_atomic_store(hw32 + row * 128 + (U >> 1), pvs[r],
                           __ATOMIC_RELAXED, __HIP_MEMORY_SCOPE_AGENT);
    }

    // publish: drain ONLY the h stores, then the slot flag
    asm volatile("s_waitcnt vmcnt(0)" ::: "memory");
    if (lane == 0)
      __hip_atomic_store(fmine, s + 1, __ATOMIC_RELAXED, __HIP_MEMORY_SCOPE_AGENT);

    // off-critical-path: outputs + next-step xg prefetch
#pragma unroll
    for (int r = 0; r < 4; ++r) {
      const int row = quad * 4 + r;
      const int b = mh * 16 + row;
      const size_t oidx = (((size_t)b * Tn + t) << 9) + scan * Hn + U;
      if constexpr (!LAYER1) {
        if (!(lane & 1)) *(unsigned*)(h0out + oidx) = pvs[r];
      } else {
        float pkf = __shfl_xor(hvs[r], 1);
        if (!(lane & 1)) { float2 st = {hvs[r], pkf}; *(float2*)(dout + oidx) = st; }
      }
    }
    {
      const unsigned short* xbn = xg + scanoff + (((size_t)tn * 2 + mh) << 14) + xlane;
      xr[0] = *(const u32x4*)(xbn + 0);
      xr[1] = *(const u32x4*)(xbn + 8);
    }
  }
}

extern "C" void kernel_launch(void* const* d_in, const int* in_sizes, int n_in,
                              void* d_out, int out_size, void* d_ws, size_t ws_size,
                              hipStream_t stream) {
  (void)in_sizes; (void)n_in; (void)out_size; (void)ws_size;
  const float* x      = (const float*)d_in[0];
  const float* Wih_f0 = (const float*)d_in[1];
  const float* Whh_f0 = (const float*)d_in[2];
  const float* b_f0   = (const float*)d_in[3];
  const float* Wih_r0 = (const float*)d_in[4];
  const float* Whh_r0 = (const float*)d_in[5];
  const float* b_r0   = (const float*)d_in[6];
  const float* Wih_f1 = (const float*)d_in[7];
  const float* Whh_f1 = (const float*)d_in[8];
  const float* b_f1   = (const float*)d_in[9];
  const float* Wih_r1 = (const float*)d_in[10];
  const float* Whh_r1 = (const float*)d_in[11];
  const float* b_r1   = (const float*)d_in[12];

  char* ws = (char*)d_ws;
  unsigned short* xgbuf = (unsigned short*)ws;                 // 268,435,456 B
  size_t off = (size_t)2 * Tn * Bn * 1024 * sizeof(unsigned short);
  unsigned short* h0out = (unsigned short*)(ws + off);         // 67,108,864 B
  off += (size_t)Bn * Tn * 512 * sizeof(unsigned short);
  unsigned short* hxbuf = (unsigned short*)(ws + off);         // 65,536 B
  off += 65536;
  int* flagsA = (int*)(ws + off);                              // 64 + 64 ints
  int* flagsB = flagsA + 64;

  hipMemsetAsync(flagsA, 0, 512, stream);  // both layers' flags -> 0

  dim3 blkA(256), blkB(512);
  // layer 0
  xg_gemm<256, true><<<dim3(4096), blkA, 0, stream>>>(
      (const void*)x, Wih_f0, b_f0, Wih_r0, b_r0, xgbuf);
  lstm_scan<false><<<dim3(8), blkB, 0, stream>>>(
      xgbuf, Whh_f0, Whh_r0, hxbuf, flagsA, h0out, (float*)nullptr);
  // layer 1
  xg_gemm<512, false><<<dim3(4096), blkA, 0, stream>>>(
      (const void*)h0out, Wih_f1, b_f1, Wih_r1, b_r1, xgbuf);
  lstm_scan<true><<<dim3(8), blkB, 0, stream>>>(
      xgbuf, Whh_f1, Whh_r1, hxbuf, flagsB, (unsigned short*)nullptr, (float*)d_out);
}